// Round 15
// baseline (1285.590 us; speedup 1.0000x reference)
//
#include <hip/hip_runtime.h>
#include <hip/hip_bf16.h>

#define NT 1024     // tokens per batch
#define DD 384      // embed dim
#define FF 64       // ff dim

typedef __attribute__((ext_vector_type(8))) _Float16 half8;
typedef __attribute__((ext_vector_type(4))) float f32x4;
typedef __attribute__((ext_vector_type(4))) unsigned uint32x4;

#define LO_SCALE 2048.f
#define INV2048  4.8828125e-4f   // 1/2048

__device__ __forceinline__ float tanh_fast(float x){
    x = fminf(fmaxf(x, -15.f), 15.f);
    float e = __expf(2.f*x);
    return (e - 1.f) * __builtin_amdgcn_rcpf(e + 1.f);
}

__device__ __forceinline__ unsigned short h2u(_Float16 h){ return __builtin_bit_cast(unsigned short, h); }

// 2-way fp16 split (Ootomo-Yokota): x ~= hi + lo/2048, hi=RTN fp16, lo=fp16((x-hi)*2048).
__device__ __forceinline__ unsigned short split2_comp(float x, int comp){
    _Float16 hi = (_Float16)x;                       // v_cvt_f16_f32 (RTN)
    if (comp == 0) return h2u(hi);
    float r = (x - (float)hi) * LO_SCALE;
    _Float16 lo = (_Float16)r;
    return h2u(lo);
}

__device__ __forceinline__ void split_pack4(const float* v, unsigned* ph, unsigned* pl){
#pragma unroll
    for (int p=0;p<2;++p){
        float a=v[2*p], b=v[2*p+1];
        _Float16 ha=(_Float16)a, hb=(_Float16)b;     // RTN hi
        ph[p] = (unsigned)h2u(ha) | ((unsigned)h2u(hb)<<16);
        float ra=(a-(float)ha)*LO_SCALE, rb=(b-(float)hb)*LO_SCALE;
        pl[p] = __builtin_bit_cast(unsigned, __builtin_amdgcn_cvt_pkrtz(ra, rb));
    }
}

// ---------------- Prep: fragment-ordered 2-split fp16 weights ----------------
// comp-major: the hi component is the first contiguous half of each table so
// k_ode can stage it into LDS with a plain memcpy.
__global__ void k_prep(const float* __restrict__ W1, const float* __restrict__ W2,
                       const float* __restrict__ W3, unsigned short* __restrict__ F)
{
    unsigned short* W1F = F;
    unsigned short* W2F = F + 49152;
    unsigned short* W3F = F + 57344;
    const int t = blockIdx.x*256 + threadIdx.x;
    const int NTH = gridDim.x*256;
    for (int i=t; i<49152; i+=NTH){
        int j=i&7, l=(i>>3)&63, u=i>>9;
        int kb=u%12, v=u/12, mb=v&3, comp=v>>2;
        int k=kb*32+8*(l>>4)+j, c=mb*16+(l&15);
        W1F[i] = split2_comp(W1[k*64+c], comp);
    }
    for (int i=t; i<8192; i+=NTH){
        int j=i&7, l=(i>>3)&63, u=i>>9;
        int kb=u&1, v=u>>1, mb=v&3, comp=v>>2;
        int k=kb*32+8*(l>>4)+j, c=mb*16+(l&15);
        W2F[i] = split2_comp(W2[k*64+c], comp);
    }
    for (int i=t; i<49152; i+=NTH){
        int j=i&7, l=(i>>3)&63, u=i>>9;
        int kb=u&1, v=u>>1, mb=v%24, comp=v/24;
        int k=kb*32+8*(l>>4)+j, c=mb*16+(l&15);
        W3F[i] = split2_comp(W3[k*384+c], comp);
    }
}

// ---------------- Prep-E: fragment-ordered fp16 embeddings (for MFMA PV) ----
__global__ void k_prepE(const float* __restrict__ emb, unsigned short* __restrict__ EF)
{
    __shared__ float tile[32][388];   // +4 pad
    const int b   = blockIdx.x >> 5;
    const int kb  = blockIdx.x & 31;
    const int tid = threadIdx.x;      // 256
    const float* src = emb + ((long long)b*NT + kb*32)*DD;
    for (int o = tid; o < 32*96; o += 256){
        int r = o/96, c4 = (o%96)*4;
        *(float4*)&tile[r][c4] = *(const float4*)&src[r*384 + c4];
    }
    __syncthreads();
    unsigned short* dst = EF + ((long long)b*24*32 + kb)*512;
    for (int o = tid; o < 24*512; o += 256){
        int mb = o >> 9, q = o & 511;
        int l = q >> 3, jj = q & 7;
        float v = tile[8*(l>>4)+jj][mb*16 + (l&15)];
        dst[(long long)mb*16384 + q] = h2u((_Float16)v);
    }
}

// 3 MFMAs per f32-accurate product: HH -> ACC, HL+LH (carry 2048x) -> ACC2.
#define MFMA3(AH,AL,BH,BL,ACC,ACC2) do{ \
    ACC  = __builtin_amdgcn_mfma_f32_16x16x32_f16(AH,BH,ACC,0,0,0); \
    ACC2 = __builtin_amdgcn_mfma_f32_16x16x32_f16(AH,BL,ACC2,0,0,0); \
    ACC2 = __builtin_amdgcn_mfma_f32_16x16x32_f16(AL,BH,ACC2,0,0,0); \
}while(0)

struct AF { half8 h, l; };
#define LDA(P, CS) AF{ *(const half8*)(P), *(const half8*)((P)+(CS)) }
#define LDB(BASE, KB) do{ \
    bh = *(const half8*)((BASE) + (KB)*2048); \
    bl = *(const half8*)((BASE) + (KB)*2048 + 1024); \
}while(0)

// ---------------- Kernel 1: RK4 ODE + scores (MFMA, 2-split fp16) ----------------
// ROUND-15: R14 base (1266us) + barrier-drain prefetch: every __syncthreads
// drains vmcnt(0), so globals issued BEFORE a barrier complete during the
// sync for free. Two cold-start chains eliminated:
//   1. M1's initial lo loads (l0..l3, stage-invariant addresses) issued
//      before the hf barrier -- M1 starts hot.
//   2. SEC0+SEC1's W3 fragments (constant addresses) issued before the x2
//      barrier (low-pressure M2 region) -- M3 starts hot.
// TRIPWIRE: WRITE_SIZE MBs = hoists pushed a region over 128 VGPR -> revert.
__global__ __launch_bounds__(512) __attribute__((amdgpu_waves_per_eu(2,2)))
void k_ode(const float* __restrict__ emb,
           const float* __restrict__ W1,
           const float* __restrict__ b1, const float* __restrict__ b2,
           const float* __restrict__ b3, const float* __restrict__ Ws,
           const float* __restrict__ bs,
           const unsigned short* __restrict__ W1F,
           const unsigned short* __restrict__ W2F,
           const unsigned short* __restrict__ W3F,
           float* __restrict__ scores)
{
    extern __shared__ char smem[];
    unsigned short* hf  = (unsigned short*)smem;   // [kb12][comp2][nb2][512] u16 = 48 KB
    unsigned short* x1f = hf  + 24576;             // 8 KB
    unsigned short* x2f = x1f + 4096;              // 8 KB
    unsigned short* w1h = x2f + 4096;              // W1F hi copy, 24576 u16 = 48 KB @65536
    float*          h0l = (float*)(smem + 114688); // [32][324] f32 (t=0..4) = 40.5 KB
    float*          cst = (float*)(smem + 156160); // b1|b2|wt|b3 = 576 f = 2.25 KB
                                                   // total 158464 B

    const float* cb1 = cst;
    const float* cb2 = cst + 64;
    const float* cwt = cst + 128;
    const float* cb3 = cst + 192;

    unsigned* hf32  = (unsigned*)hf;
    unsigned* x1f32 = (unsigned*)x1f;
    unsigned* x2f32 = (unsigned*)x2f;

    const int tid  = threadIdx.x;
    const int lane = tid & 63;
    const int w    = __builtin_amdgcn_readfirstlane(tid >> 6);
    const int g    = lane >> 4;          // 0..3
    const int rr   = lane & 15;
    const int nb   = w & 1;
    const int mbA  = w >> 1;             // 0..3
    const int rowl = nb*16 + rr;         // 0..31
    const long long row0 = (long long)blockIdx.x * 32;
    const float dt = 0.1f;

    // stage W1F hi-components (48 KB) + small constants into LDS
    {
        const unsigned* srcw = (const unsigned*)W1F;
        unsigned* dstw = (unsigned*)w1h;
        for (int o = tid; o < 12288; o += 512) dstw[o] = srcw[o];
        for (int o = tid; o < 576; o += 512){
            float v;
            if      (o < 64)  v = b1[o];
            else if (o < 128) v = b2[o-64];
            else if (o < 192) v = W1[384*64 + (o-128)];
            else              v = b3[o-192];
            cst[o] = v;
        }
    }

    // fragment read bases (u16)
    const unsigned short* hrd  = hf  + nb*512 + lane*8;
    const unsigned short* x1rd = x1f + nb*512 + lane*8;
    const unsigned short* x2rd = x2f + nb*512 + lane*8;
    // fragment write base (u32); kb stride 1024 u32, lo comp at +512 u32
    const unsigned wxp = nb*256 + rr*4 + 2*(g&1);
    const unsigned wx1 = ((unsigned)(mbA>>1))*1024 + 64u*((2*mbA+(g>>1))&3) + wxp;
    // h0: t=0..4 in LDS (stride 324/row, 2-way-free banks, 16B aligned); t=5 in regs
    const int h0base = rowl*324 + mbA*80 + 4*g;
    float h0r5[4];

    // loop-invariant global bases for the barrier-drain prefetches
    const unsigned short* L1B = W1F + 24576 + mbA*6144 + lane*8;  // M1 lo stream
    const unsigned short* A30 = W3F + (unsigned)((6*mbA+0)*2)*512 + lane*8;  // SEC0
    const unsigned short* A31 = W3F + (unsigned)((6*mbA+1)*2)*512 + lane*8;  // SEC1

    // state init: h0 -> LDS/regs, htmp fragments -> LDS; arc stays in registers
    float arc[24];
#pragma unroll
    for (int t=0;t<6;++t){
        f32x4 v = *(const f32x4*)(emb + (row0+rowl)*DD + mbA*96 + t*16 + 4*g);
        float hw[4] = {v[0],v[1],v[2],v[3]};
        if (t < 5) *(float4*)(h0l + h0base + 16*t) = make_float4(hw[0],hw[1],hw[2],hw[3]);
        else {
#pragma unroll
            for (int r=0;r<4;++r) h0r5[r] = hw[r];
        }
        unsigned ph[2],pl[2];
        split_pack4(hw,ph,pl);
        const unsigned wh = ((unsigned)((6*mbA+t)>>1))*1024 + 64u*((2*t+(g>>1))&3) + wxp;
        *(uint2*)(hf32 + wh       ) = make_uint2(ph[0],ph[1]);
        *(uint2*)(hf32 + wh +  512) = make_uint2(pl[0],pl[1]);
    }

// M3 section (T>=2): 6 MFMAs for output block T; b3 acc from LDS cache.
// sched_barrier stops cross-section hoisting.
#define M3SEC(T, ACC, ACC2) do{ \
    ACC = *(const f32x4*)(cb3 + mbA*96 + 16*(T) + 4*g); \
    ACC2 = (f32x4){0.f,0.f,0.f,0.f}; \
    const unsigned short* A3 = W3F + (unsigned)((6*mbA+(T))*2)*512 + lane*8; \
    AF w0 = LDA(A3, 24576); \
    AF w1 = LDA(A3+512, 24576); \
    MFMA3(w0.h,w0.l,B0h,B0l,ACC,ACC2); \
    MFMA3(w1.h,w1.l,B1h,B1l,ACC,ACC2); \
    __builtin_amdgcn_sched_barrier(0); \
}while(0)

// M3 section with PRELOADED W3 fragments (SEC0/SEC1, hoisted above x2 barrier)
#define M3SECP(T, ACC, ACC2, W0, W1R) do{ \
    ACC = *(const f32x4*)(cb3 + mbA*96 + 16*(T) + 4*g); \
    ACC2 = (f32x4){0.f,0.f,0.f,0.f}; \
    MFMA3(W0.h,W0.l,B0h,B0l,ACC,ACC2); \
    MFMA3(W1R.h,W1R.l,B1h,B1l,ACC,ACC2); \
    __builtin_amdgcn_sched_barrier(0); \
}while(0)

// RK4 update for block t: combine hi/lo accs, h0 from LDS (t<5) or regs (t=5),
// accumulate arc, write htmp frags
#define M3UPD(T, ACC, ACC2) do{ \
    float h0v[4]; \
    if ((T) < 5){ \
        f32x4 _hv = *(const f32x4*)(h0l + h0base + 16*(T)); \
        h0v[0]=_hv[0]; h0v[1]=_hv[1]; h0v[2]=_hv[2]; h0v[3]=_hv[3]; \
    } else { \
        _Pragma("unroll") \
        for (int r=0;r<4;++r) h0v[r] = h0r5[r]; \
    } \
    float hw[4]; \
    if (stage < 3){ \
        _Pragma("unroll") \
        for (int r=0;r<4;++r){ float kr=fmaf(ACC2[r], INV2048, ACC[r]); \
            arc[4*(T)+r] = fmaf(wacc, kr, arc[4*(T)+r]); \
            hw[r] = fmaf(cs, kr, h0v[r]); } \
    } else { \
        _Pragma("unroll") \
        for (int r=0;r<4;++r){ float kr=fmaf(ACC2[r], INV2048, ACC[r]); \
            arc[4*(T)+r] = fmaf(wacc, kr, arc[4*(T)+r]); \
            hw[r] = h0v[r] + arc[4*(T)+r]; } \
        if ((T) < 5) *(float4*)(h0l + h0base + 16*(T)) = make_float4(hw[0],hw[1],hw[2],hw[3]); \
        else { \
            _Pragma("unroll") \
            for (int r=0;r<4;++r) h0r5[r] = hw[r]; \
        } \
    } \
    unsigned ph[2],pl[2]; \
    split_pack4(hw,ph,pl); \
    const unsigned wh = ((unsigned)((6*mbA+(T))>>1))*1024 + 64u*((2*(T)+(g>>1))&3) + wxp; \
    *(uint2*)(hf32 + wh       ) = make_uint2(ph[0],ph[1]); \
    *(uint2*)(hf32 + wh +  512) = make_uint2(pl[0],pl[1]); \
}while(0)

#pragma unroll 1
    for (int step=0; step<10; ++step){
        const float tstep = dt*(float)step;
#pragma unroll
        for (int j=0;j<24;++j) arc[j]=0.f;

#pragma unroll 1
        for (int stage=0; stage<4; ++stage){
            const float ts = tstep + ((stage==0)?0.f:((stage==3)?dt:0.5f*dt));

            // barrier-drain prefetch: M1's first 4 lo fragments (addresses are
            // stage-invariant). The hf barrier's vmcnt(0) drain completes them.
            half8 l0 = *(const half8*)(L1B);
            half8 l1 = *(const half8*)(L1B + 512);
            half8 l2 = *(const half8*)(L1B + 1024);
            half8 l3 = *(const half8*)(L1B + 1536);

            __syncthreads();   // htmp fragments ready (also covers staging copies)

            // ---------- M1^T: x1 = tanh([htmp,t]@W1 + b1) ----------
            // hi A-frags from LDS; lo A-frags depth-2 tapered prefetch (initial
            // 4 preloaded above); B-frags JIT ds_read; accL split.
            f32x4 accA, accB, accLA, accLB;
            AF c0, c1;   // M2's W2 fragments, hoisted above the x1 barrier
            {
                f32x4 b1v = *(const f32x4*)(cb1 + mbA*16 + 4*g);
                f32x4 wtv = *(const f32x4*)(cwt + mbA*16 + 4*g);
#pragma unroll
                for (int r=0;r<4;++r){ accA[r] = fmaf(ts, wtv[r], b1v[r]); accB[r] = 0.f; accLA[r] = 0.f; accLB[r] = 0.f; }
            }
            {
                const unsigned short* H1 = w1h + mbA*6144 + lane*8;          // LDS hi
#pragma unroll 1
                for (int p=0;p<4;++p){
                    half8 hh0 = *(const half8*)(H1 + (2*p)*512);
                    half8 hh1 = *(const half8*)(H1 + (2*p+1)*512);
                    half8 bh,bl;
                    LDB(hrd, 2*p);
                    MFMA3(hh0,l0,bh,bl,accA,accLA);
                    LDB(hrd, 2*p+1);
                    MFMA3(hh1,l1,bh,bl,accB,accLB);
                    l0 = l2; l1 = l3;
                    l2 = *(const half8*)(L1B + (2*p+4)*512);
                    l3 = *(const half8*)(L1B + (2*p+5)*512);
                }
                // p=4: kb8/kb9 (in l0/l1); shift kb10/11; NO new loads
                {
                    half8 hh0 = *(const half8*)(H1 + 8*512);
                    half8 hh1 = *(const half8*)(H1 + 9*512);
                    half8 bh,bl;
                    LDB(hrd, 8);
                    MFMA3(hh0,l0,bh,bl,accA,accLA);
                    LDB(hrd, 9);
                    MFMA3(hh1,l1,bh,bl,accB,accLB);
                    l0 = l2; l1 = l3;
                }
                // p=5: kb10/kb11
                {
                    half8 hh0 = *(const half8*)(H1 + 10*512);
                    half8 hh1 = *(const half8*)(H1 + 11*512);
                    half8 bh,bl;
                    LDB(hrd, 10);
                    MFMA3(hh0,l0,bh,bl,accA,accLA);
                    LDB(hrd, 11);
                    MFMA3(hh1,l1,bh,bl,accB,accLB);
                }
            }
            // hoist M2's W2 fragment loads: independent of x1, their latency
            // hides under the tanh/split/write tail + barrier drain
            {
                const unsigned short* A2 = W2F + mbA*1024 + lane*8;
                c0 = LDA(A2, 4096);
                c1 = LDA(A2 + 512, 4096);
            }
            {
                float xv[4];
#pragma unroll
                for (int r=0;r<4;++r) xv[r] = tanh_fast(accA[r] + accB[r] + (accLA[r]+accLB[r])*INV2048);
                unsigned ph[2],pl[2];
                split_pack4(xv,ph,pl);
                *(uint2*)(x1f32 + wx1       ) = make_uint2(ph[0],ph[1]);
                *(uint2*)(x1f32 + wx1 +  512) = make_uint2(pl[0],pl[1]);
            }
            __syncthreads();   // x1 ready

            // ---------- M2^T: x2 = tanh(x1@W2 + b2) ----------
            f32x4 acc2 = *(const f32x4*)(cb2 + mbA*16 + 4*g);
            f32x4 acc2L;
            {
#pragma unroll
                for (int r=0;r<4;++r) acc2L[r] = 0.f;
                half8 bh,bl;
                LDB(x1rd, 0);
                MFMA3(c0.h,c0.l,bh,bl,acc2,acc2L);
                LDB(x1rd, 1);
                MFMA3(c1.h,c1.l,bh,bl,acc2,acc2L);
            }
            // barrier-drain prefetch: SEC0+SEC1's W3 fragments (constant
            // addresses); x2 barrier's drain completes them -> M3 starts hot.
            AF s0w0 = LDA(A30, 24576);
            AF s0w1 = LDA(A30+512, 24576);
            AF s1w0 = LDA(A31, 24576);
            AF s1w1 = LDA(A31+512, 24576);
            {
                float xv[4];
#pragma unroll
                for (int r=0;r<4;++r) xv[r] = tanh_fast(acc2[r] + acc2L[r]*INV2048);
                unsigned ph[2],pl[2];
                split_pack4(xv,ph,pl);
                *(uint2*)(x2f32 + wx1       ) = make_uint2(ph[0],ph[1]);
                *(uint2*)(x2f32 + wx1 +  512) = make_uint2(pl[0],pl[1]);
            }
            __syncthreads();   // x2 ready

            // ---------- M3^T + RK4, 6 sections interleaved SEC(t+1) || UPD(t) ----------
            const float wacc = (dt/6.f)*((stage==1||stage==2)?2.f:1.f);
            const float cs   = (stage==2)?dt:0.5f*dt;
            {
                half8 B0h = *(const half8*)(x2rd);
                half8 B0l = *(const half8*)(x2rd + 1024);
                half8 B1h = *(const half8*)(x2rd + 2048);
                half8 B1l = *(const half8*)(x2rd + 3072);
                f32x4 ac0,ac1,ac2b,ac3,ac4,ac5;      // hi accs (b3 from LDS in SEC)
                f32x4 c0v,c1v,c2v,c3v,c4v,c5v;       // lo accumulators
                M3SECP(0, ac0, c0v, s0w0, s0w1);
                M3SECP(1, ac1, c1v, s1w0, s1w1);  M3UPD(0, ac0, c0v);
                M3SEC(2, ac2b, c2v);  M3UPD(1, ac1, c1v);
                M3SEC(3, ac3, c3v);   M3UPD(2, ac2b, c2v);
                M3SEC(4, ac4, c4v);   M3UPD(3, ac3, c3v);
                M3SEC(5, ac5, c5v);   M3UPD(4, ac4, c4v);
                M3UPD(5, ac5, c5v);
            }
        } // stage
    } // step

    // ---------- scores = h_final @ Ws + bs ----------
    float part = 0.f;
#pragma unroll
    for (int t=0;t<6;++t){
        float hv[4];
        if (t < 5){
            f32x4 _hv = *(const f32x4*)(h0l + h0base + 16*t);
            hv[0]=_hv[0]; hv[1]=_hv[1]; hv[2]=_hv[2]; hv[3]=_hv[3];
        } else {
#pragma unroll
            for (int r=0;r<4;++r) hv[r] = h0r5[r];
        }
        f32x4 wsv = *(const f32x4*)(Ws + mbA*96 + t*16 + 4*g);
#pragma unroll
        for (int r=0;r<4;++r) part = fmaf(hv[r], wsv[r], part);
    }
    __syncthreads();                       // all LDS matmul reads done
    float* red = (float*)x1f;              // reuse x1f space (2 KB needed)
    red[rowl*16 + mbA*4 + g] = part;
    __syncthreads();
    if (tid < 32){
        float s = bs[0];
#pragma unroll
        for (int q=0;q<16;++q) s += red[tid*16+q];
        scores[row0 + tid] = s;
    }
#undef M3SEC
#undef M3SECP
#undef M3UPD
}

// ---------------- Kernel 2: row_sum[b][i] = sum_j |s_i - s_j| ----------------
__global__ void k_rowsum(const float* __restrict__ scores, float* __restrict__ rs)
{
    __shared__ float s[NT];
    const int b   = blockIdx.x >> 2;
    const int q   = blockIdx.x & 3;
    const int tid = threadIdx.x;
    for (int i=tid; i<NT; i+=256) s[i] = scores[b*NT + i];
    __syncthreads();
    const int i = q*256 + tid;
    const float si = s[i];
    float sum = 0.f;
#pragma unroll 8
    for (int j=0; j<NT; ++j) sum += fabsf(si - s[j]);
    rs[b*NT + i] = sum;
}

// ---------------- Kernel 3 (MFMA): out = softmax(P_max/TAU) @ emb ----------------
__global__ __launch_bounds__(512)
void k_pvm(const unsigned short* __restrict__ EF, const float* __restrict__ scores,
           const float* __restrict__ rs, float* __restrict__ out)
{
    __shared__ float s_tr[2*NT];          // interleaved {t_i, r_i} * (1/TAU/ln2)
    __shared__ float red_m[16][33];
    __shared__ float red_s[16][33];
    __shared__ float s_MI[64];            // M2[32] | I[32]

    const int tid = threadIdx.x;
    const int b   = blockIdx.x >> 5;
    const int j0  = (blockIdx.x & 31) * 32;
    const float invT2 = 10.f * 1.44269504f;   // (1/TAU)*log2(e)

    for (int i = tid; i < NT; i += 512){
        s_tr[2*i  ] =  scores[b*NT + i] * invT2;
        s_tr[2*i+1] = -rs[b*NT + i] * invT2;
    }
    __syncthreads();

    {
        const int jl = tid & 31;
        const int ch = tid >> 5;          // 0..15
        const float SC = 1023.f - 2.f*(float)(j0 + jl);
        const int ib = ch*64;
        float m = -3.0e38f;
#pragma unroll 4
        for (int i = ib; i < ib+64; ++i)
            m = fmaxf(m, fmaf(s_tr[2*i], SC, s_tr[2*i+1]));
        float sum = 0.f;
#pragma unroll 4
        for (int i = ib; i < ib+64; ++i)
            sum += exp2f(fmaf(s_tr[2*i], SC, s_tr[2*i+1]) - m);
        red_m[ch][jl] = m; red_s[ch][jl] = sum;
    }
    __syncthreads();
    if (tid < 32){
        float M = -3.0e38f;
#pragma unroll
        for (int c=0;c<16;++c) M = fmaxf(M, red_m[c][tid]);
        float S = 0.f;
#pragma unroll
        for (int c=0;c<16;++c) S += red_s[c][tid] * exp2f(red_m[c][tid] - M);
        s_MI[tid]    = M;
        s_MI[32+tid] = __builtin_amdgcn_rcpf(S);   // S >= 1
    }
    __syncthreads();

    const int lane = tid & 63;
    const int w    = __builtin_amdgcn_readfirstlane(tid >> 6);
    const int g    = lane >> 4;
    const int rr   = lane & 15;
    const int nb   = w & 1;
    const int mbA  = w >> 1;
    const int jl   = nb*16 + rr;
    const float SCv = 1023.f - 2.f*(float)(j0 + jl);
    const float Mv  = s_MI[jl];
    const float Iv  = s_MI[32 + jl];

    f32x4 ac0={0,0,0,0}, ac1={0,0,0,0}, ac2={0,0,0,0},
          ac3={0,0,0,0}, ac4={0,0,0,0}, ac5={0,0,0,0};

    const unsigned short* Abase = EF + (((long long)b*24 + mbA*6)*32)*512 + lane*8;

#pragma unroll 2
    for (int kb = 0; kb < 32; ++kb){
        const float* str = s_tr + 2*(kb*32 + 8*g);
        uint32x4 pw;
#pragma unroll
        for (int p=0;p<4;++p){
            float L0 = fmaf(str[4*p  ], SCv, str[4*p+1]) - Mv;
            float L1 = fmaf(str[4*p+2], SCv, str[4*p+3]) - Mv;
            pw[p] = __builtin_bit_cast(unsigned,
                        __builtin_amdgcn_cvt_pkrtz(exp2f(L0), exp2f(L1)));
        }
        half8 Pf = __builtin_bit_cast(half8, pw);
        const unsigned short* A = Abase + kb*512;
        ac0 = __builtin_amdgcn_mfma_f32_16x16x32_f16(*(const half8*)(A          ), Pf, ac0, 0,0,0);
        ac1 = __builtin_amdgcn_mfma_f32_16x16x32_f16(*(const half8*)(A + 16384  ), Pf, ac1, 0,0,0);
        ac2 = __builtin_amdgcn_mfma_f32_16x16x32_f16(*(const half8*)(A + 2*16384), Pf, ac2, 0,0,0);
        ac3 = __builtin_amdgcn_mfma_f32_16x16x32_f16(*(const half8*)(A + 3*16384), Pf, ac3, 0,0,0);
        ac4 = __builtin_amdgcn_mfma_f32_16x16x32_f16(*(const half8*)(A + 4*16384), Pf, ac4, 0,0,0);
        ac5 = __builtin_amdgcn_mfma_f32_16x16x32_f16(*(const half8*)(A + 5*16384), Pf, ac5, 0,0,0);
    }

    float* op = out + ((long long)b*NT + j0 + jl)*DD + mbA*96 + 4*g;
    *(float4*)(op       ) = make_float4(ac0[0]*Iv, ac0[1]*Iv, ac0[2]*Iv, ac0[3]*Iv);
    *(float4*)(op + 16  ) = make_float4(ac1[0]*Iv, ac1[1]*Iv, ac1[2]*Iv, ac1[3]*Iv);
    *(float4*)(op + 32  ) = make_float4(ac2[0]*Iv, ac2[1]*Iv, ac2[2]*Iv, ac2[3]*Iv);
    *(float4*)(op + 48  ) = make_float4(ac3[0]*Iv, ac3[1]*Iv, ac3[2]*Iv, ac3[3]*Iv);
    *(float4*)(op + 64  ) = make_float4(ac4[0]*Iv, ac4[1]*Iv, ac4[2]*Iv, ac4[3]*Iv);
    *(float4*)(op + 80  ) = make_float4(ac5[0]*Iv, ac5[1]*Iv, ac5[2]*Iv, ac5[3]*Iv);
}

// ---------------- Kernel 3 (fallback, fp32 VALU): kept for ws_size guard ----
__global__ __launch_bounds__(256, 2)
void k_pv(const float* __restrict__ emb, const float* __restrict__ scores,
          const float* __restrict__ rs, float* __restrict__ out)
{
    __shared__ float s_tt[NT];
    __shared__ float s_rp[NT];
    __shared__ float red_m[8][33];
    __shared__ float red_s[8][33];
    __shared__ float s_M[32], s_I[32];

    const int tid = threadIdx.x;
    const int b   = blockIdx.x >> 5;
    const int j0  = (blockIdx.x & 31) * 32;
    const float invT = 10.f;   // 1/TAU

    for (int i=tid; i<NT; i+=256){
        s_tt[i] =  scores[b*NT + i] * invT;
        s_rp[i] = -rs[b*NT + i] * invT;
    }
    __syncthreads();
    {
        const int jl = tid & 31;
        const int ch = tid >> 5;
        const float SC = 1023.f - 2.f*(float)(j0 + jl);
        const int ibeg = ch*128;
        float m = -3.0e38f;
#pragma unroll 4
        for (int i=ibeg; i<ibeg+128; ++i){
            float L = fmaf(s_tt[i], SC, s_rp[i]);
            m = fmaxf(m, L);
        }
        float sum = 0.f;
#pragma unroll 4
        for (int i=ibeg; i<ibeg+128; ++i){
            float L = fmaf(s_tt[i], SC, s_rp[i]);
            sum += __expf(L - m);
        }
        red_m[ch][jl] = m; red_s[ch][jl] = sum;
    }
    __syncthreads();
    if (tid < 32){
        float M = -3.0e38f;
#pragma unroll
        for (int c=0; c<8; ++c) M = fmaxf(M, red_m[c][tid]);
        float S = 0.f;
#pragma unroll
        for (int c=0; c<8; ++c) S += red_s[c][tid]*__expf(red_m[c][tid]-M);
        s_M[tid] = M;
        s_I[tid] = 1.f/S;
    }
    __syncthreads();

    const int tx = tid & 31;
    const int jy = tid >> 5;
    float accv[4][12];
#pragma unroll
    for (int v=0; v<4; ++v)
#pragma unroll
        for (int u=0; u<12; ++u) accv[v][u] = 0.f;

    float SCv[4], Mv[4], Iv[4];
#pragma unroll
    for (int v=0; v<4; ++v){
        const int jl = jy + 8*v;
        SCv[v] = 1023.f - 2.f*(float)(j0 + jl);
        Mv[v]  = s_M[jl];
        Iv[v]  = s_I[jl];
    }
    const float* ep = emb + ((long long)b*NT)*DD + tx;
#pragma unroll 2
    for (int i=0; i<NT; ++i){
        const float ti = s_tt[i], ri = s_rp[i];
        float ev[12];
#pragma unroll
        for (int u=0; u<12; ++u) ev[u] = ep[(long long)i*DD + 32*u];
        float p[4];
#pragma unroll
        for (int v=0; v<4; ++v)
            p[v] = __expf(fmaf(ti, SCv[v], ri) - Mv[v]);
#pragma unroll
        for (int v=0; v<4; ++v)
#pragma unroll
            for (int u=0; u<12; ++u) accv[v][u] = fmaf(p[v], ev[u], accv[v][u]);
    }
#pragma unroll
    for (int v=0; v<4; ++v){
        float* op = out + ((long long)b*NT + j0 + jy + 8*v)*DD + tx;
#pragma unroll
        for (int u=0; u<12; ++u) op[32*u] = accv[v][u]*Iv[v];
    }
}

extern "C" void kernel_launch(void* const* d_in, const int* in_sizes, int n_in,
                              void* d_out, int out_size, void* d_ws, size_t ws_size,
                              hipStream_t stream)
{
    const float* emb = (const float*)d_in[0];
    const float* W1  = (const float*)d_in[1];
    const float* b1  = (const float*)d_in[2];
    const float* W2  = (const float*)d_in[3];
    const float* b2  = (const float*)d_in[4];
    const float* W3  = (const float*)d_in[5];
    const float* b3  = (const float*)d_in[6];
    const float* Ws  = (const float*)d_in[7];
    const float* bs  = (const float*)d_in[8];

    const int B = in_sizes[0] / (NT*DD);
    float* out    = (float*)d_out;
    float* scores = out + (long long)B*NT*DD;   // scores tail of output

    unsigned short* WF = (unsigned short*)d_ws;     // W1F | W2F | W3F (fp16 2-split)
    const unsigned short* W1F = WF;
    const unsigned short* W2F = WF + 49152;
    const unsigned short* W3F = WF + 57344;
    float* rsum = (float*)((char*)d_ws + 319488);   // B*NT floats

    const size_t efOff = 589824;                    // after WF+rsum, 4KB-aligned
    const size_t efBytes = (size_t)B*24*32*512*2;   // fragment-ordered fp16 emb
    const bool useMFMApv = (ws_size >= efOff + efBytes);
    unsigned short* EF = (unsigned short*)((char*)d_ws + efOff);

    const int ODE_LDS = 158464;   // 154.75 KB dynamic LDS, 1 block/CU
    hipFuncSetAttribute(reinterpret_cast<const void*>(k_ode),
                        hipFuncAttributeMaxDynamicSharedMemorySize, ODE_LDS);

    hipLaunchKernelGGL(k_prep, dim3(64), dim3(256), 0, stream, W1, W2, W3, WF);
    if (useMFMApv)
        hipLaunchKernelGGL(k_prepE, dim3(B*32), dim3(256), 0, stream, emb, EF);
    hipLaunchKernelGGL(k_ode, dim3(B*NT/32), dim3(512), ODE_LDS, stream,
                       emb, W1, b1, b2, b3, Ws, bs, W1F, W2F, W3F, scores);
    hipLaunchKernelGGL(k_rowsum, dim3(B*4), dim3(256), 0, stream, scores, rsum);
    if (useMFMApv)
        hipLaunchKernelGGL(k_pvm, dim3(B*32), dim3(512), 0, stream, EF, scores, rsum, out);
    else
        hipLaunchKernelGGL(k_pv, dim3(B*32), dim3(256), 0, stream, emb, scores, rsum, out);
}

// Round 16
// 1262.928 us; speedup vs baseline: 1.0179x; 1.0179x over previous
//
#include <hip/hip_runtime.h>
#include <hip/hip_bf16.h>

#define NT 1024     // tokens per batch
#define DD 384      // embed dim
#define FF 64       // ff dim

typedef __attribute__((ext_vector_type(8))) _Float16 half8;
typedef __attribute__((ext_vector_type(4))) float f32x4;
typedef __attribute__((ext_vector_type(4))) unsigned uint32x4;

#define LO_SCALE 2048.f
#define INV2048  4.8828125e-4f   // 1/2048

__device__ __forceinline__ float tanh_fast(float x){
    x = fminf(fmaxf(x, -15.f), 15.f);
    float e = __expf(2.f*x);
    return (e - 1.f) * __builtin_amdgcn_rcpf(e + 1.f);
}

__device__ __forceinline__ unsigned short h2u(_Float16 h){ return __builtin_bit_cast(unsigned short, h); }

// 2-way fp16 split (Ootomo-Yokota): x ~= hi + lo/2048, hi=RTN fp16, lo=fp16((x-hi)*2048).
__device__ __forceinline__ unsigned short split2_comp(float x, int comp){
    _Float16 hi = (_Float16)x;                       // v_cvt_f16_f32 (RTN)
    if (comp == 0) return h2u(hi);
    float r = (x - (float)hi) * LO_SCALE;
    _Float16 lo = (_Float16)r;
    return h2u(lo);
}

__device__ __forceinline__ void split_pack4(const float* v, unsigned* ph, unsigned* pl){
#pragma unroll
    for (int p=0;p<2;++p){
        float a=v[2*p], b=v[2*p+1];
        _Float16 ha=(_Float16)a, hb=(_Float16)b;     // RTN hi
        ph[p] = (unsigned)h2u(ha) | ((unsigned)h2u(hb)<<16);
        float ra=(a-(float)ha)*LO_SCALE, rb=(b-(float)hb)*LO_SCALE;
        pl[p] = __builtin_bit_cast(unsigned, __builtin_amdgcn_cvt_pkrtz(ra, rb));
    }
}

// ---------------- Prep: fragment-ordered 2-split fp16 weights ----------------
// comp-major: the hi component is the first contiguous half of each table so
// k_ode can stage it into LDS with a plain memcpy.
__global__ void k_prep(const float* __restrict__ W1, const float* __restrict__ W2,
                       const float* __restrict__ W3, unsigned short* __restrict__ F)
{
    unsigned short* W1F = F;
    unsigned short* W2F = F + 49152;
    unsigned short* W3F = F + 57344;
    const int t = blockIdx.x*256 + threadIdx.x;
    const int NTH = gridDim.x*256;
    for (int i=t; i<49152; i+=NTH){
        int j=i&7, l=(i>>3)&63, u=i>>9;
        int kb=u%12, v=u/12, mb=v&3, comp=v>>2;
        int k=kb*32+8*(l>>4)+j, c=mb*16+(l&15);
        W1F[i] = split2_comp(W1[k*64+c], comp);
    }
    for (int i=t; i<8192; i+=NTH){
        int j=i&7, l=(i>>3)&63, u=i>>9;
        int kb=u&1, v=u>>1, mb=v&3, comp=v>>2;
        int k=kb*32+8*(l>>4)+j, c=mb*16+(l&15);
        W2F[i] = split2_comp(W2[k*64+c], comp);
    }
    for (int i=t; i<49152; i+=NTH){
        int j=i&7, l=(i>>3)&63, u=i>>9;
        int kb=u&1, v=u>>1, mb=v%24, comp=v/24;
        int k=kb*32+8*(l>>4)+j, c=mb*16+(l&15);
        W3F[i] = split2_comp(W3[k*384+c], comp);
    }
}

// ---------------- Prep-E: fragment-ordered fp16 embeddings (for MFMA PV) ----
__global__ void k_prepE(const float* __restrict__ emb, unsigned short* __restrict__ EF)
{
    __shared__ float tile[32][388];   // +4 pad
    const int b   = blockIdx.x >> 5;
    const int kb  = blockIdx.x & 31;
    const int tid = threadIdx.x;      // 256
    const float* src = emb + ((long long)b*NT + kb*32)*DD;
    for (int o = tid; o < 32*96; o += 256){
        int r = o/96, c4 = (o%96)*4;
        *(float4*)&tile[r][c4] = *(const float4*)&src[r*384 + c4];
    }
    __syncthreads();
    unsigned short* dst = EF + ((long long)b*24*32 + kb)*512;
    for (int o = tid; o < 24*512; o += 256){
        int mb = o >> 9, q = o & 511;
        int l = q >> 3, jj = q & 7;
        float v = tile[8*(l>>4)+jj][mb*16 + (l&15)];
        dst[(long long)mb*16384 + q] = h2u((_Float16)v);
    }
}

// 3 MFMAs per f32-accurate product: HH -> ACC, HL+LH (carry 2048x) -> ACC2.
#define MFMA3(AH,AL,BH,BL,ACC,ACC2) do{ \
    ACC  = __builtin_amdgcn_mfma_f32_16x16x32_f16(AH,BH,ACC,0,0,0); \
    ACC2 = __builtin_amdgcn_mfma_f32_16x16x32_f16(AH,BL,ACC2,0,0,0); \
    ACC2 = __builtin_amdgcn_mfma_f32_16x16x32_f16(AL,BH,ACC2,0,0,0); \
}while(0)

struct AF { half8 h, l; };
#define LDA(P, CS) AF{ *(const half8*)(P), *(const half8*)((P)+(CS)) }
#define LDB(BASE, KB) do{ \
    bh = *(const half8*)((BASE) + (KB)*2048); \
    bl = *(const half8*)((BASE) + (KB)*2048 + 1024); \
}while(0)

// ---------------- Kernel 1: RK4 ODE + scores (MFMA, 2-split fp16) ----------------
// ROUND-16: revert to R14 (verified best, 1266us). R15's barrier-drain
// prefetch REGRESSED (+20us): loads issued before __syncthreads DELAY barrier
// arrival (each wave drains vmcnt(0) before signaling) -- they serialize into
// the sync instead of hiding under it. R14's placement (loads after barriers,
// or followed by dependent-free VALU) was already optimal.
// Structure: W1-hi + small-constants in LDS, depth-2 tapered lo prefetch,
// c0/c1 hoist, h0 t<5 in LDS / t=5 in regs. 154.75 KB LDS, 1 block/CU.
__global__ __launch_bounds__(512) __attribute__((amdgpu_waves_per_eu(2,2)))
void k_ode(const float* __restrict__ emb,
           const float* __restrict__ W1,
           const float* __restrict__ b1, const float* __restrict__ b2,
           const float* __restrict__ b3, const float* __restrict__ Ws,
           const float* __restrict__ bs,
           const unsigned short* __restrict__ W1F,
           const unsigned short* __restrict__ W2F,
           const unsigned short* __restrict__ W3F,
           float* __restrict__ scores)
{
    extern __shared__ char smem[];
    unsigned short* hf  = (unsigned short*)smem;   // [kb12][comp2][nb2][512] u16 = 48 KB
    unsigned short* x1f = hf  + 24576;             // 8 KB
    unsigned short* x2f = x1f + 4096;              // 8 KB
    unsigned short* w1h = x2f + 4096;              // W1F hi copy, 24576 u16 = 48 KB @65536
    float*          h0l = (float*)(smem + 114688); // [32][324] f32 (t=0..4) = 40.5 KB
    float*          cst = (float*)(smem + 156160); // b1|b2|wt|b3 = 576 f = 2.25 KB
                                                   // total 158464 B

    const float* cb1 = cst;
    const float* cb2 = cst + 64;
    const float* cwt = cst + 128;
    const float* cb3 = cst + 192;

    unsigned* hf32  = (unsigned*)hf;
    unsigned* x1f32 = (unsigned*)x1f;
    unsigned* x2f32 = (unsigned*)x2f;

    const int tid  = threadIdx.x;
    const int lane = tid & 63;
    const int w    = __builtin_amdgcn_readfirstlane(tid >> 6);
    const int g    = lane >> 4;          // 0..3
    const int rr   = lane & 15;
    const int nb   = w & 1;
    const int mbA  = w >> 1;             // 0..3
    const int rowl = nb*16 + rr;         // 0..31
    const long long row0 = (long long)blockIdx.x * 32;
    const float dt = 0.1f;

    // stage W1F hi-components (48 KB) + small constants into LDS
    {
        const unsigned* srcw = (const unsigned*)W1F;
        unsigned* dstw = (unsigned*)w1h;
        for (int o = tid; o < 12288; o += 512) dstw[o] = srcw[o];
        for (int o = tid; o < 576; o += 512){
            float v;
            if      (o < 64)  v = b1[o];
            else if (o < 128) v = b2[o-64];
            else if (o < 192) v = W1[384*64 + (o-128)];
            else              v = b3[o-192];
            cst[o] = v;
        }
    }

    // fragment read bases (u16)
    const unsigned short* hrd  = hf  + nb*512 + lane*8;
    const unsigned short* x1rd = x1f + nb*512 + lane*8;
    const unsigned short* x2rd = x2f + nb*512 + lane*8;
    // fragment write base (u32); kb stride 1024 u32, lo comp at +512 u32
    const unsigned wxp = nb*256 + rr*4 + 2*(g&1);
    const unsigned wx1 = ((unsigned)(mbA>>1))*1024 + 64u*((2*mbA+(g>>1))&3) + wxp;
    // h0: t=0..4 in LDS (stride 324/row, 2-way-free banks, 16B aligned); t=5 in regs
    const int h0base = rowl*324 + mbA*80 + 4*g;
    float h0r5[4];

    // state init: h0 -> LDS/regs, htmp fragments -> LDS; arc stays in registers
    float arc[24];
#pragma unroll
    for (int t=0;t<6;++t){
        f32x4 v = *(const f32x4*)(emb + (row0+rowl)*DD + mbA*96 + t*16 + 4*g);
        float hw[4] = {v[0],v[1],v[2],v[3]};
        if (t < 5) *(float4*)(h0l + h0base + 16*t) = make_float4(hw[0],hw[1],hw[2],hw[3]);
        else {
#pragma unroll
            for (int r=0;r<4;++r) h0r5[r] = hw[r];
        }
        unsigned ph[2],pl[2];
        split_pack4(hw,ph,pl);
        const unsigned wh = ((unsigned)((6*mbA+t)>>1))*1024 + 64u*((2*t+(g>>1))&3) + wxp;
        *(uint2*)(hf32 + wh       ) = make_uint2(ph[0],ph[1]);
        *(uint2*)(hf32 + wh +  512) = make_uint2(pl[0],pl[1]);
    }

// M3 section: 6 MFMAs for output block t; ACC initialized from the b3 LDS
// cache (broadcast read, no global latency). sched_barrier stops
// cross-section hoisting.
#define M3SEC(T, ACC, ACC2) do{ \
    ACC = *(const f32x4*)(cb3 + mbA*96 + 16*(T) + 4*g); \
    ACC2 = (f32x4){0.f,0.f,0.f,0.f}; \
    const unsigned short* A3 = W3F + (unsigned)((6*mbA+(T))*2)*512 + lane*8; \
    AF w0 = LDA(A3, 24576); \
    AF w1 = LDA(A3+512, 24576); \
    MFMA3(w0.h,w0.l,B0h,B0l,ACC,ACC2); \
    MFMA3(w1.h,w1.l,B1h,B1l,ACC,ACC2); \
    __builtin_amdgcn_sched_barrier(0); \
}while(0)

// RK4 update for block t: combine hi/lo accs, h0 from LDS (t<5) or regs (t=5),
// accumulate arc, write htmp frags
#define M3UPD(T, ACC, ACC2) do{ \
    float h0v[4]; \
    if ((T) < 5){ \
        f32x4 _hv = *(const f32x4*)(h0l + h0base + 16*(T)); \
        h0v[0]=_hv[0]; h0v[1]=_hv[1]; h0v[2]=_hv[2]; h0v[3]=_hv[3]; \
    } else { \
        _Pragma("unroll") \
        for (int r=0;r<4;++r) h0v[r] = h0r5[r]; \
    } \
    float hw[4]; \
    if (stage < 3){ \
        _Pragma("unroll") \
        for (int r=0;r<4;++r){ float kr=fmaf(ACC2[r], INV2048, ACC[r]); \
            arc[4*(T)+r] = fmaf(wacc, kr, arc[4*(T)+r]); \
            hw[r] = fmaf(cs, kr, h0v[r]); } \
    } else { \
        _Pragma("unroll") \
        for (int r=0;r<4;++r){ float kr=fmaf(ACC2[r], INV2048, ACC[r]); \
            arc[4*(T)+r] = fmaf(wacc, kr, arc[4*(T)+r]); \
            hw[r] = h0v[r] + arc[4*(T)+r]; } \
        if ((T) < 5) *(float4*)(h0l + h0base + 16*(T)) = make_float4(hw[0],hw[1],hw[2],hw[3]); \
        else { \
            _Pragma("unroll") \
            for (int r=0;r<4;++r) h0r5[r] = hw[r]; \
        } \
    } \
    unsigned ph[2],pl[2]; \
    split_pack4(hw,ph,pl); \
    const unsigned wh = ((unsigned)((6*mbA+(T))>>1))*1024 + 64u*((2*(T)+(g>>1))&3) + wxp; \
    *(uint2*)(hf32 + wh       ) = make_uint2(ph[0],ph[1]); \
    *(uint2*)(hf32 + wh +  512) = make_uint2(pl[0],pl[1]); \
}while(0)

#pragma unroll 1
    for (int step=0; step<10; ++step){
        const float tstep = dt*(float)step;
#pragma unroll
        for (int j=0;j<24;++j) arc[j]=0.f;

#pragma unroll 1
        for (int stage=0; stage<4; ++stage){
            const float ts = tstep + ((stage==0)?0.f:((stage==3)?dt:0.5f*dt));
            __syncthreads();   // htmp fragments ready (also covers staging copies)

            // ---------- M1^T: x1 = tanh([htmp,t]@W1 + b1) ----------
            // hi A-frags from LDS; lo A-frags depth-2 TAPERED prefetch (no
            // wasted end-of-stage loads); B-frags JIT ds_read; accL split.
            f32x4 accA, accB, accLA, accLB;
            AF c0, c1;   // M2's W2 fragments, hoisted above the x1 barrier
            {
                f32x4 b1v = *(const f32x4*)(cb1 + mbA*16 + 4*g);
                f32x4 wtv = *(const f32x4*)(cwt + mbA*16 + 4*g);
#pragma unroll
                for (int r=0;r<4;++r){ accA[r] = fmaf(ts, wtv[r], b1v[r]); accB[r] = 0.f; accLA[r] = 0.f; accLB[r] = 0.f; }
            }
            {
                const unsigned short* H1 = w1h + mbA*6144 + lane*8;          // LDS hi
                const unsigned short* L1 = W1F + 24576 + mbA*6144 + lane*8;  // global lo
                half8 l0 = *(const half8*)(L1);
                half8 l1 = *(const half8*)(L1 + 512);
                half8 l2 = *(const half8*)(L1 + 1024);
                half8 l3 = *(const half8*)(L1 + 1536);
#pragma unroll 1
                for (int p=0;p<4;++p){
                    half8 hh0 = *(const half8*)(H1 + (2*p)*512);
                    half8 hh1 = *(const half8*)(H1 + (2*p+1)*512);
                    half8 bh,bl;
                    LDB(hrd, 2*p);
                    MFMA3(hh0,l0,bh,bl,accA,accLA);
                    LDB(hrd, 2*p+1);
                    MFMA3(hh1,l1,bh,bl,accB,accLB);
                    l0 = l2; l1 = l3;
                    l2 = *(const half8*)(L1 + (2*p+4)*512);
                    l3 = *(const half8*)(L1 + (2*p+5)*512);
                }
                // p=4: kb8/kb9 (in l0/l1); shift kb10/11; NO new loads
                {
                    half8 hh0 = *(const half8*)(H1 + 8*512);
                    half8 hh1 = *(const half8*)(H1 + 9*512);
                    half8 bh,bl;
                    LDB(hrd, 8);
                    MFMA3(hh0,l0,bh,bl,accA,accLA);
                    LDB(hrd, 9);
                    MFMA3(hh1,l1,bh,bl,accB,accLB);
                    l0 = l2; l1 = l3;
                }
                // p=5: kb10/kb11
                {
                    half8 hh0 = *(const half8*)(H1 + 10*512);
                    half8 hh1 = *(const half8*)(H1 + 11*512);
                    half8 bh,bl;
                    LDB(hrd, 10);
                    MFMA3(hh0,l0,bh,bl,accA,accLA);
                    LDB(hrd, 11);
                    MFMA3(hh1,l1,bh,bl,accB,accLB);
                }
            }
            // hoist M2's W2 fragment loads: independent of x1, their latency
            // hides under the tanh/split/write tail + barrier drain
            {
                const unsigned short* A2 = W2F + mbA*1024 + lane*8;
                c0 = LDA(A2, 4096);
                c1 = LDA(A2 + 512, 4096);
            }
            {
                float xv[4];
#pragma unroll
                for (int r=0;r<4;++r) xv[r] = tanh_fast(accA[r] + accB[r] + (accLA[r]+accLB[r])*INV2048);
                unsigned ph[2],pl[2];
                split_pack4(xv,ph,pl);
                *(uint2*)(x1f32 + wx1       ) = make_uint2(ph[0],ph[1]);
                *(uint2*)(x1f32 + wx1 +  512) = make_uint2(pl[0],pl[1]);
            }
            __syncthreads();   // x1 ready

            // ---------- M2^T: x2 = tanh(x1@W2 + b2) ----------
            f32x4 acc2 = *(const f32x4*)(cb2 + mbA*16 + 4*g);
            f32x4 acc2L;
            {
#pragma unroll
                for (int r=0;r<4;++r) acc2L[r] = 0.f;
                half8 bh,bl;
                LDB(x1rd, 0);
                MFMA3(c0.h,c0.l,bh,bl,acc2,acc2L);
                LDB(x1rd, 1);
                MFMA3(c1.h,c1.l,bh,bl,acc2,acc2L);
            }
            {
                float xv[4];
#pragma unroll
                for (int r=0;r<4;++r) xv[r] = tanh_fast(acc2[r] + acc2L[r]*INV2048);
                unsigned ph[2],pl[2];
                split_pack4(xv,ph,pl);
                *(uint2*)(x2f32 + wx1       ) = make_uint2(ph[0],ph[1]);
                *(uint2*)(x2f32 + wx1 +  512) = make_uint2(pl[0],pl[1]);
            }
            __syncthreads();   // x2 ready

            // ---------- M3^T + RK4, 6 sections interleaved SEC(t+1) || UPD(t) ----------
            const float wacc = (dt/6.f)*((stage==1||stage==2)?2.f:1.f);
            const float cs   = (stage==2)?dt:0.5f*dt;
            {
                half8 B0h = *(const half8*)(x2rd);
                half8 B0l = *(const half8*)(x2rd + 1024);
                half8 B1h = *(const half8*)(x2rd + 2048);
                half8 B1l = *(const half8*)(x2rd + 3072);
                f32x4 ac0,ac1,ac2b,ac3,ac4,ac5;      // hi accs (b3 from LDS in SEC)
                f32x4 c0v,c1v,c2v,c3v,c4v,c5v;       // lo accumulators
                M3SEC(0, ac0, c0v);
                M3SEC(1, ac1, c1v);   M3UPD(0, ac0, c0v);
                M3SEC(2, ac2b, c2v);  M3UPD(1, ac1, c1v);
                M3SEC(3, ac3, c3v);   M3UPD(2, ac2b, c2v);
                M3SEC(4, ac4, c4v);   M3UPD(3, ac3, c3v);
                M3SEC(5, ac5, c5v);   M3UPD(4, ac4, c4v);
                M3UPD(5, ac5, c5v);
            }
        } // stage
    } // step

    // ---------- scores = h_final @ Ws + bs ----------
    float part = 0.f;
#pragma unroll
    for (int t=0;t<6;++t){
        float hv[4];
        if (t < 5){
            f32x4 _hv = *(const f32x4*)(h0l + h0base + 16*t);
            hv[0]=_hv[0]; hv[1]=_hv[1]; hv[2]=_hv[2]; hv[3]=_hv[3];
        } else {
#pragma unroll
            for (int r=0;r<4;++r) hv[r] = h0r5[r];
        }
        f32x4 wsv = *(const f32x4*)(Ws + mbA*96 + t*16 + 4*g);
#pragma unroll
        for (int r=0;r<4;++r) part = fmaf(hv[r], wsv[r], part);
    }
    __syncthreads();                       // all LDS matmul reads done
    float* red = (float*)x1f;              // reuse x1f space (2 KB needed)
    red[rowl*16 + mbA*4 + g] = part;
    __syncthreads();
    if (tid < 32){
        float s = bs[0];
#pragma unroll
        for (int q=0;q<16;++q) s += red[tid*16+q];
        scores[row0 + tid] = s;
    }
#undef M3SEC
#undef M3UPD
}

// ---------------- Kernel 2: row_sum[b][i] = sum_j |s_i - s_j| ----------------
__global__ void k_rowsum(const float* __restrict__ scores, float* __restrict__ rs)
{
    __shared__ float s[NT];
    const int b   = blockIdx.x >> 2;
    const int q   = blockIdx.x & 3;
    const int tid = threadIdx.x;
    for (int i=tid; i<NT; i+=256) s[i] = scores[b*NT + i];
    __syncthreads();
    const int i = q*256 + tid;
    const float si = s[i];
    float sum = 0.f;
#pragma unroll 8
    for (int j=0; j<NT; ++j) sum += fabsf(si - s[j]);
    rs[b*NT + i] = sum;
}

// ---------------- Kernel 3 (MFMA): out = softmax(P_max/TAU) @ emb ----------------
__global__ __launch_bounds__(512)
void k_pvm(const unsigned short* __restrict__ EF, const float* __restrict__ scores,
           const float* __restrict__ rs, float* __restrict__ out)
{
    __shared__ float s_tr[2*NT];          // interleaved {t_i, r_i} * (1/TAU/ln2)
    __shared__ float red_m[16][33];
    __shared__ float red_s[16][33];
    __shared__ float s_MI[64];            // M2[32] | I[32]

    const int tid = threadIdx.x;
    const int b   = blockIdx.x >> 5;
    const int j0  = (blockIdx.x & 31) * 32;
    const float invT2 = 10.f * 1.44269504f;   // (1/TAU)*log2(e)

    for (int i = tid; i < NT; i += 512){
        s_tr[2*i  ] =  scores[b*NT + i] * invT2;
        s_tr[2*i+1] = -rs[b*NT + i] * invT2;
    }
    __syncthreads();

    {
        const int jl = tid & 31;
        const int ch = tid >> 5;          // 0..15
        const float SC = 1023.f - 2.f*(float)(j0 + jl);
        const int ib = ch*64;
        float m = -3.0e38f;
#pragma unroll 4
        for (int i = ib; i < ib+64; ++i)
            m = fmaxf(m, fmaf(s_tr[2*i], SC, s_tr[2*i+1]));
        float sum = 0.f;
#pragma unroll 4
        for (int i = ib; i < ib+64; ++i)
            sum += exp2f(fmaf(s_tr[2*i], SC, s_tr[2*i+1]) - m);
        red_m[ch][jl] = m; red_s[ch][jl] = sum;
    }
    __syncthreads();
    if (tid < 32){
        float M = -3.0e38f;
#pragma unroll
        for (int c=0;c<16;++c) M = fmaxf(M, red_m[c][tid]);
        float S = 0.f;
#pragma unroll
        for (int c=0;c<16;++c) S += red_s[c][tid] * exp2f(red_m[c][tid] - M);
        s_MI[tid]    = M;
        s_MI[32+tid] = __builtin_amdgcn_rcpf(S);   // S >= 1
    }
    __syncthreads();

    const int lane = tid & 63;
    const int w    = __builtin_amdgcn_readfirstlane(tid >> 6);
    const int g    = lane >> 4;
    const int rr   = lane & 15;
    const int nb   = w & 1;
    const int mbA  = w >> 1;
    const int jl   = nb*16 + rr;
    const float SCv = 1023.f - 2.f*(float)(j0 + jl);
    const float Mv  = s_MI[jl];
    const float Iv  = s_MI[32 + jl];

    f32x4 ac0={0,0,0,0}, ac1={0,0,0,0}, ac2={0,0,0,0},
          ac3={0,0,0,0}, ac4={0,0,0,0}, ac5={0,0,0,0};

    const unsigned short* Abase = EF + (((long long)b*24 + mbA*6)*32)*512 + lane*8;

#pragma unroll 2
    for (int kb = 0; kb < 32; ++kb){
        const float* str = s_tr + 2*(kb*32 + 8*g);
        uint32x4 pw;
#pragma unroll
        for (int p=0;p<4;++p){
            float L0 = fmaf(str[4*p  ], SCv, str[4*p+1]) - Mv;
            float L1 = fmaf(str[4*p+2], SCv, str[4*p+3]) - Mv;
            pw[p] = __builtin_bit_cast(unsigned,
                        __builtin_amdgcn_cvt_pkrtz(exp2f(L0), exp2f(L1)));
        }
        half8 Pf = __builtin_bit_cast(half8, pw);
        const unsigned short* A = Abase + kb*512;
        ac0 = __builtin_amdgcn_mfma_f32_16x16x32_f16(*(const half8*)(A          ), Pf, ac0, 0,0,0);
        ac1 = __builtin_amdgcn_mfma_f32_16x16x32_f16(*(const half8*)(A + 16384  ), Pf, ac1, 0,0,0);
        ac2 = __builtin_amdgcn_mfma_f32_16x16x32_f16(*(const half8*)(A + 2*16384), Pf, ac2, 0,0,0);
        ac3 = __builtin_amdgcn_mfma_f32_16x16x32_f16(*(const half8*)(A + 3*16384), Pf, ac3, 0,0,0);
        ac4 = __builtin_amdgcn_mfma_f32_16x16x32_f16(*(const half8*)(A + 4*16384), Pf, ac4, 0,0,0);
        ac5 = __builtin_amdgcn_mfma_f32_16x16x32_f16(*(const half8*)(A + 5*16384), Pf, ac5, 0,0,0);
    }

    float* op = out + ((long long)b*NT + j0 + jl)*DD + mbA*96 + 4*g;
    *(float4*)(op       ) = make_float4(ac0[0]*Iv, ac0[1]*Iv, ac0[2]*Iv, ac0[3]*Iv);
    *(float4*)(op + 16  ) = make_float4(ac1[0]*Iv, ac1[1]*Iv, ac1[2]*Iv, ac1[3]*Iv);
    *(float4*)(op + 32  ) = make_float4(ac2[0]*Iv, ac2[1]*Iv, ac2[2]*Iv, ac2[3]*Iv);
    *(float4*)(op + 48  ) = make_float4(ac3[0]*Iv, ac3[1]*Iv, ac3[2]*Iv, ac3[3]*Iv);
    *(float4*)(op + 64  ) = make_float4(ac4[0]*Iv, ac4[1]*Iv, ac4[2]*Iv, ac4[3]*Iv);
    *(float4*)(op + 80  ) = make_float4(ac5[0]*Iv, ac5[1]*Iv, ac5[2]*Iv, ac5[3]*Iv);
}

// ---------------- Kernel 3 (fallback, fp32 VALU): kept for ws_size guard ----
__global__ __launch_bounds__(256, 2)
void k_pv(const float* __restrict__ emb, const float* __restrict__ scores,
          const float* __restrict__ rs, float* __restrict__ out)
{
    __shared__ float s_tt[NT];
    __shared__ float s_rp[NT];
    __shared__ float red_m[8][33];
    __shared__ float red_s[8][33];
    __shared__ float s_M[32], s_I[32];

    const int tid = threadIdx.x;
    const int b   = blockIdx.x >> 5;
    const int j0  = (blockIdx.x & 31) * 32;
    const float invT = 10.f;   // 1/TAU

    for (int i=tid; i<NT; i+=256){
        s_tt[i] =  scores[b*NT + i] * invT;
        s_rp[i] = -rs[b*NT + i] * invT;
    }
    __syncthreads();
    {
        const int jl = tid & 31;
        const int ch = tid >> 5;
        const float SC = 1023.f - 2.f*(float)(j0 + jl);
        const int ibeg = ch*128;
        float m = -3.0e38f;
#pragma unroll 4
        for (int i=ibeg; i<ibeg+128; ++i){
            float L = fmaf(s_tt[i], SC, s_rp[i]);
            m = fmaxf(m, L);
        }
        float sum = 0.f;
#pragma unroll 4
        for (int i=ibeg; i<ibeg+128; ++i){
            float L = fmaf(s_tt[i], SC, s_rp[i]);
            sum += __expf(L - m);
        }
        red_m[ch][jl] = m; red_s[ch][jl] = sum;
    }
    __syncthreads();
    if (tid < 32){
        float M = -3.0e38f;
#pragma unroll
        for (int c=0; c<8; ++c) M = fmaxf(M, red_m[c][tid]);
        float S = 0.f;
#pragma unroll
        for (int c=0; c<8; ++c) S += red_s[c][tid]*__expf(red_m[c][tid]-M);
        s_M[tid] = M;
        s_I[tid] = 1.f/S;
    }
    __syncthreads();

    const int tx = tid & 31;
    const int jy = tid >> 5;
    float accv[4][12];
#pragma unroll
    for (int v=0; v<4; ++v)
#pragma unroll
        for (int u=0; u<12; ++u) accv[v][u] = 0.f;

    float SCv[4], Mv[4], Iv[4];
#pragma unroll
    for (int v=0; v<4; ++v){
        const int jl = jy + 8*v;
        SCv[v] = 1023.f - 2.f*(float)(j0 + jl);
        Mv[v]  = s_M[jl];
        Iv[v]  = s_I[jl];
    }
    const float* ep = emb + ((long long)b*NT)*DD + tx;
#pragma unroll 2
    for (int i=0; i<NT; ++i){
        const float ti = s_tt[i], ri = s_rp[i];
        float ev[12];
#pragma unroll
        for (int u=0; u<12; ++u) ev[u] = ep[(long long)i*DD + 32*u];
        float p[4];
#pragma unroll
        for (int v=0; v<4; ++v)
            p[v] = __expf(fmaf(ti, SCv[v], ri) - Mv[v]);
#pragma unroll
        for (int v=0; v<4; ++v)
#pragma unroll
            for (int u=0; u<12; ++u) accv[v][u] = fmaf(p[v], ev[u], accv[v][u]);
    }
#pragma unroll
    for (int v=0; v<4; ++v){
        float* op = out + ((long long)b*NT + j0 + jy + 8*v)*DD + tx;
#pragma unroll
        for (int u=0; u<12; ++u) op[32*u] = accv[v][u]*Iv[v];
    }
}

extern "C" void kernel_launch(void* const* d_in, const int* in_sizes, int n_in,
                              void* d_out, int out_size, void* d_ws, size_t ws_size,
                              hipStream_t stream)
{
    const float* emb = (const float*)d_in[0];
    const float* W1  = (const float*)d_in[1];
    const float* b1  = (const float*)d_in[2];
    const float* W2  = (const float*)d_in[3];
    const float* b2  = (const float*)d_in[4];
    const float* W3  = (const float*)d_in[5];
    const float* b3  = (const float*)d_in[6];
    const float* Ws  = (const float*)d_in[7];
    const float* bs  = (const float*)d_in[8];

    const int B = in_sizes[0] / (NT*DD);
    float* out    = (float*)d_out;
    float* scores = out + (long long)B*NT*DD;   // scores tail of output

    unsigned short* WF = (unsigned short*)d_ws;     // W1F | W2F | W3F (fp16 2-split)
    const unsigned short* W1F = WF;
    const unsigned short* W2F = WF + 49152;
    const unsigned short* W3F = WF + 57344;
    float* rsum = (float*)((char*)d_ws + 319488);   // B*NT floats

    const size_t efOff = 589824;                    // after WF+rsum, 4KB-aligned
    const size_t efBytes = (size_t)B*24*32*512*2;   // fragment-ordered fp16 emb
    const bool useMFMApv = (ws_size >= efOff + efBytes);
    unsigned short* EF = (unsigned short*)((char*)d_ws + efOff);

    const int ODE_LDS = 158464;   // 154.75 KB dynamic LDS, 1 block/CU
    hipFuncSetAttribute(reinterpret_cast<const void*>(k_ode),
                        hipFuncAttributeMaxDynamicSharedMemorySize, ODE_LDS);

    hipLaunchKernelGGL(k_prep, dim3(64), dim3(256), 0, stream, W1, W2, W3, WF);
    if (useMFMApv)
        hipLaunchKernelGGL(k_prepE, dim3(B*32), dim3(256), 0, stream, emb, EF);
    hipLaunchKernelGGL(k_ode, dim3(B*NT/32), dim3(512), ODE_LDS, stream,
                       emb, W1, b1, b2, b3, Ws, bs, W1F, W2F, W3F, scores);
    hipLaunchKernelGGL(k_rowsum, dim3(B*4), dim3(256), 0, stream, scores, rsum);
    if (useMFMApv)
        hipLaunchKernelGGL(k_pvm, dim3(B*32), dim3(512), 0, stream, EF, scores, rsum, out);
    else
        hipLaunchKernelGGL(k_pv, dim3(B*32), dim3(256), 0, stream, emb, scores, rsum, out);
}